// Round 1
// baseline (341.295 us; speedup 1.0000x reference)
//
#include <hip/hip_runtime.h>
#include <hip/hip_bf16.h>

typedef __bf16 bf16_t;
typedef __attribute__((ext_vector_type(8))) __bf16 bf16x8;
typedef __attribute__((ext_vector_type(4))) float f32x4;
typedef __attribute__((ext_vector_type(8))) short s16x8;
typedef __attribute__((ext_vector_type(4))) float float4_t;

__device__ __forceinline__ float gelu_approx(float x) {
    // x * sigmoid(1.5957691216*x + 0.0713548163*x^3)  (tanh-form GELU)
    float u2 = x * fmaf(x * x, 0.0713548163f, 1.5957691216f);
    float e  = __expf(-u2);
    return x * __builtin_amdgcn_rcpf(1.0f + e);
}

#define MFMA16(a, b, c) __builtin_amdgcn_mfma_f32_16x16x32_bf16((a), (b), (c), 0, 0, 0)

__global__ __launch_bounds__(256, 2)
void nmlp_conv_kernel(const float* __restrict__ in_f,
                      const float* __restrict__ out_f,
                      const float* __restrict__ W1,
                      const float* __restrict__ b1,
                      const float* __restrict__ W2,
                      const float* __restrict__ b2,
                      const int* __restrict__ nbr,
                      const int* __restrict__ rsp,
                      float* __restrict__ out,
                      int M)
{
    __shared__ alignas(16) float wstage[64 * 128];   // 32 KiB; reused later for h staging
    const int tid   = threadIdx.x;
    const int lane  = tid & 63;
    const int wslot = tid >> 6;
    const int g = lane >> 4;   // k-group 0..3
    const int c = lane & 15;   // A-row / B-col / D-col

    // ---- stage W1 (fp32) to LDS coalesced, build bf16 register fragments ----
    {
        const float4_t* src = (const float4_t*)W1;
        float4_t* dst = (float4_t*)wstage;
        #pragma unroll
        for (int i = 0; i < 8; ++i) dst[tid + 256 * i] = src[tid + 256 * i];
    }
    __syncthreads();
    bf16x8 w1f[8][2];   // [n-tile][k-step], W1[32k+8g+j][16t+c]
    #pragma unroll
    for (int t = 0; t < 8; ++t)
        #pragma unroll
        for (int k = 0; k < 2; ++k)
            #pragma unroll
            for (int j = 0; j < 8; ++j)
                w1f[t][k][j] = (bf16_t)wstage[(32 * k + 8 * g + j) * 128 + 16 * t + c];
    __syncthreads();
    {
        const float4_t* src = (const float4_t*)W2;
        float4_t* dst = (float4_t*)wstage;
        #pragma unroll
        for (int i = 0; i < 8; ++i) dst[tid + 256 * i] = src[tid + 256 * i];
    }
    __syncthreads();
    bf16x8 w2f[4][4];   // [n-tile][k-step], W2[32k+8g+j][16u+c]
    #pragma unroll
    for (int u = 0; u < 4; ++u)
        #pragma unroll
        for (int k = 0; k < 4; ++k)
            #pragma unroll
            for (int j = 0; j < 8; ++j)
                w2f[u][k][j] = (bf16_t)wstage[(32 * k + 8 * g + j) * 64 + 16 * u + c];
    __syncthreads();

    float b1r[8];
    #pragma unroll
    for (int t = 0; t < 8; ++t) b1r[t] = b1[16 * t + c];
    float b2r[4];
    #pragma unroll
    for (int u = 0; u < 4; ++u) b2r[u] = b2[16 * u + c];

    // per-wave h staging: [16 rows][128 cols] bf16 = 4 KiB, XOR-swizzled
    bf16_t* hlds = (bf16_t*)wstage + wslot * 2048;

    const int nw = gridDim.x * 4;
    for (int s = blockIdx.x * 4 + wslot; s < M; s += nw) {
        const int e0 = rsp[s], e1 = rsp[s + 1];
        const int d = e1 - e0;
        float* orow = out + (size_t)s * 64;
        if (d <= 0) {
            if (g == 0) {
                #pragma unroll
                for (int u = 0; u < 4; ++u) orow[u * 16 + c] = 0.0f;
            }
            continue;
        }

        // hoisted self-feature fragment (k = 32..63 of agg), same for all rows
        bf16x8 a1;
        {
            const float4_t* sp = (const float4_t*)(out_f + (size_t)s * 32 + 8 * g);
            float4_t s0 = sp[0], s1 = sp[1];
            a1[0] = (bf16_t)s0.x; a1[1] = (bf16_t)s0.y; a1[2] = (bf16_t)s0.z; a1[3] = (bf16_t)s0.w;
            a1[4] = (bf16_t)s1.x; a1[5] = (bf16_t)s1.y; a1[6] = (bf16_t)s1.z; a1[7] = (bf16_t)s1.w;
        }

        f32x4 colacc[4];
        #pragma unroll
        for (int u = 0; u < 4; ++u) colacc[u] = (f32x4){0.f, 0.f, 0.f, 0.f};

        const int ntile = (d + 15) >> 4;
        for (int T = 0; T < ntile; ++T) {
            int er = e0 + T * 16 + c;
            er = er < e1 ? er : e1 - 1;          // clamp padded rows (masked later)
            const int nb = nbr[er];

            // gathered neighbor fragment (k = 0..31 of agg)
            bf16x8 a0;
            {
                const float4_t* rp = (const float4_t*)(in_f + (size_t)nb * 32 + 8 * g);
                float4_t r0 = rp[0], r1 = rp[1];
                a0[0] = (bf16_t)r0.x; a0[1] = (bf16_t)r0.y; a0[2] = (bf16_t)r0.z; a0[3] = (bf16_t)r0.w;
                a0[4] = (bf16_t)r1.x; a0[5] = (bf16_t)r1.y; a0[6] = (bf16_t)r1.z; a0[7] = (bf16_t)r1.w;
            }

            // ---- GEMM1 (16x64 @ 64x128) + bias + GELU -> swizzled LDS ----
            #pragma unroll
            for (int t = 0; t < 8; ++t) {
                f32x4 h = {b1r[t], b1r[t], b1r[t], b1r[t]};
                h = MFMA16(a0, w1f[t][0], h);
                h = MFMA16(a1, w1f[t][1], h);
                #pragma unroll
                for (int j = 0; j < 4; ++j) {
                    float hv = gelu_approx(h[j]);
                    int r_  = 4 * g + j;          // D row (edge within tile)
                    int col = 16 * t + c;          // D col (hidden)
                    hlds[r_ * 128 + (col ^ ((r_ & 7) << 3))] = (bf16_t)hv;
                }
            }

            // ---- read h back as GEMM2 A-fragments (row = c, k = 32k2+8g+j) ----
            bf16x8 ah[4];
            #pragma unroll
            for (int k = 0; k < 4; ++k) {
                const s16x8* p = (const s16x8*)(hlds + c * 128 + ((k * 32 + g * 8) ^ ((c & 7) << 3)));
                ah[k] = __builtin_bit_cast(bf16x8, *p);
            }

            // ---- GEMM2 (16x128 @ 128x64) + bias, masked row accumulation ----
            const int rem = d - T * 16;
            #pragma unroll
            for (int u = 0; u < 4; ++u) {
                f32x4 y = {b2r[u], b2r[u], b2r[u], b2r[u]};
                #pragma unroll
                for (int k = 0; k < 4; ++k) y = MFMA16(ah[k], w2f[u][k], y);
                #pragma unroll
                for (int j = 0; j < 4; ++j)
                    colacc[u][j] += (4 * g + j < rem) ? y[j] : 0.0f;
            }
        }

        // reduce rows: 4 local + across the 4 lane-groups; then mean and store
        const float inv_d = 1.0f / (float)d;
        #pragma unroll
        for (int u = 0; u < 4; ++u) {
            float v = colacc[u][0] + colacc[u][1] + colacc[u][2] + colacc[u][3];
            v += __shfl_xor(v, 16);
            v += __shfl_xor(v, 32);
            if (g == 0) orow[u * 16 + c] = v * inv_d;
        }
    }
}

extern "C" void kernel_launch(void* const* d_in, const int* in_sizes, int n_in,
                              void* d_out, int out_size, void* d_ws, size_t ws_size,
                              hipStream_t stream) {
    const float* in_f  = (const float*)d_in[0];
    const float* out_f = (const float*)d_in[1];
    const float* W1    = (const float*)d_in[2];
    const float* b1    = (const float*)d_in[3];
    const float* W2    = (const float*)d_in[4];
    const float* b2    = (const float*)d_in[5];
    const int*   nbr   = (const int*)d_in[6];
    const int*   rsp   = (const int*)d_in[7];
    float* out = (float*)d_out;
    const int M = in_sizes[7] - 1;

    dim3 grid(1024), block(256);
    nmlp_conv_kernel<<<grid, block, 0, stream>>>(in_f, out_f, W1, b1, W2, b2,
                                                 nbr, rsp, out, M);
}

// Round 2
// 171.102 us; speedup vs baseline: 1.9947x; 1.9947x over previous
//
#include <hip/hip_runtime.h>
#include <hip/hip_bf16.h>

typedef __bf16 bf16_t;
typedef __attribute__((ext_vector_type(8))) __bf16 bf16x8;
typedef __attribute__((ext_vector_type(4))) float f32x4;
typedef __attribute__((ext_vector_type(4))) float float4_t;

#define MFMA16(a, b, c) __builtin_amdgcn_mfma_f32_16x16x32_bf16((a), (b), (c), 0, 0, 0)

__device__ __forceinline__ float gelu_fast(float x) {
    // exact-ish tanh-form GELU with -log2(e) folded: x * sigmoid(1.5958x + 0.07135x^3)
    float z = x * fmaf(x * x, -0.1029453f, -2.3022081f);
    float e = __builtin_amdgcn_exp2f(z);
    return x * __builtin_amdgcn_rcpf(1.0f + e);
}

__device__ __forceinline__ int lbound(const int* __restrict__ a, int n, int v) {
    int lo = 0, hi = n;
    while (lo < hi) { int mid = (lo + hi) >> 1; if (a[mid] < v) lo = mid + 1; else hi = mid; }
    return lo;
}

__global__ __launch_bounds__(256, 2)
void nmlp_kernel(const float* __restrict__ in_f, const float* __restrict__ out_f,
                 const float* __restrict__ W1, const float* __restrict__ b1,
                 const float* __restrict__ W2, const float* __restrict__ b2,
                 const int* __restrict__ nbr, const int* __restrict__ rsp,
                 float* __restrict__ out, int M, int E, int epw)
{
    __shared__ alignas(16) unsigned char lds[32768];
    float* wstage = (float*)lds;
    const int tid = threadIdx.x, lane = tid & 63, wslot = tid >> 6;
    const int g = lane >> 4, c = lane & 15;

    // ---- stage W1 (fp32, coalesced) -> bf16 register fragments ----
    {
        const float4_t* src = (const float4_t*)W1;
        float4_t* dst = (float4_t*)wstage;
        #pragma unroll
        for (int i = 0; i < 8; ++i) dst[tid + 256 * i] = src[tid + 256 * i];
    }
    __syncthreads();
    bf16x8 w1f[8][2];   // [n-tile][k-step]: W1[32k+8g+j][16t+c]
    #pragma unroll
    for (int t = 0; t < 8; ++t)
        #pragma unroll
        for (int k = 0; k < 2; ++k)
            #pragma unroll
            for (int j = 0; j < 8; ++j)
                w1f[t][k][j] = (bf16_t)wstage[(32 * k + 8 * g + j) * 128 + 16 * t + c];
    __syncthreads();
    {
        const float4_t* src = (const float4_t*)W2;
        float4_t* dst = (float4_t*)wstage;
        #pragma unroll
        for (int i = 0; i < 8; ++i) dst[tid + 256 * i] = src[tid + 256 * i];
    }
    __syncthreads();
    bf16x8 w2f[4][4];   // [n-tile][k-step]: W2[32k+8g+j][16u+c]
    #pragma unroll
    for (int u = 0; u < 4; ++u)
        #pragma unroll
        for (int k = 0; k < 4; ++k)
            #pragma unroll
            for (int j = 0; j < 8; ++j)
                w2f[u][k][j] = (bf16_t)wstage[(32 * k + 8 * g + j) * 64 + 16 * u + c];
    __syncthreads();

    float b1r[8], b2r[4];
    #pragma unroll
    for (int t = 0; t < 8; ++t) b1r[t] = b1[16 * t + c];
    #pragma unroll
    for (int u = 0; u < 4; ++u) b2r[u] = b2[16 * u + c];

    // per-wave h buffer: 16 rows x 272B stride (row->bank alias broken), 4352B/wave
    const unsigned hbase = (unsigned)wslot * 4352u;
    const unsigned hwb = hbase + (unsigned)(g * 1088 + 2 * c);   // write base (row=4g+j, col=16t+c)
    const unsigned hrb = hbase + (unsigned)(c * 272 + 16 * g);   // read base  (row=c, k=32k2+8g+j)

    // ---- edge-balanced segment range for this wave ----
    const int wid = blockIdx.x * 4 + wslot;
    int sA = lbound(rsp, M + 1, wid * epw);
    int sB = lbound(rsp, M + 1, wid * epw + epw);
    if (sA > M) sA = M;
    if (sB > M) sB = M;
    if (sA >= sB) return;

    int s = sA;
    int e0c = rsp[s], e1c = rsp[s + 1];
    const int eS = e0c, eE = rsp[sB];

    f32x4 colacc[4];
    #pragma unroll
    for (int u = 0; u < 4; ++u) colacc[u] = (f32x4){0.f, 0.f, 0.f, 0.f};

    if (eS < eE) {
        // prefetch tile 0: per-lane edge, neighbor index, segment id, feature rows
        int er = eS + c; if (er > eE - 1) er = eE - 1;
        int nb = nbr[er];
        int sg;
        { int lo2 = s, hi2 = sB - 1;
          while (lo2 < hi2) { int mid = (lo2 + hi2 + 1) >> 1; if (rsp[mid] <= er) lo2 = mid; else hi2 = mid - 1; }
          sg = lo2; }
        float4_t f0, f1, g0, g1;
        { const float4_t* rp = (const float4_t*)(in_f + (size_t)nb * 32 + 8 * g); f0 = rp[0]; f1 = rp[1]; }
        { const float4_t* sp = (const float4_t*)(out_f + (size_t)sg * 32 + 8 * g); g0 = sp[0]; g1 = sp[1]; }

        for (int et = eS; et < eE; et += 16) {
            const bool more = (et + 16 < eE);
            int nbN = 0, sgN = 0;
            if (more) {   // prefetch next tile's index + segment id (loads issue now)
                int erN = et + 16 + c; if (erN > eE - 1) erN = eE - 1;
                nbN = nbr[erN];
                int lo2 = s, hi2 = sB - 1;
                while (lo2 < hi2) { int mid = (lo2 + hi2 + 1) >> 1; if (rsp[mid] <= erN) lo2 = mid; else hi2 = mid - 1; }
                sgN = lo2;
            }
            // convert current operands (rows prefetched last iteration)
            bf16x8 a0, a1;
            #pragma unroll
            for (int j = 0; j < 4; ++j) {
                a0[j] = (bf16_t)f0[j]; a0[4 + j] = (bf16_t)f1[j];
                a1[j] = (bf16_t)g0[j]; a1[4 + j] = (bf16_t)g1[j];
            }
            // ---- GEMM1 + bias + GELU -> LDS (imm-offset b16 writes) ----
            #pragma unroll
            for (int t = 0; t < 8; ++t) {
                f32x4 h = {b1r[t], b1r[t], b1r[t], b1r[t]};
                h = MFMA16(a0, w1f[t][0], h);
                h = MFMA16(a1, w1f[t][1], h);
                #pragma unroll
                for (int j = 0; j < 4; ++j)
                    *(bf16_t*)(lds + hwb + j * 272 + t * 32) = (bf16_t)gelu_fast(h[j]);
            }
            // prefetch next tile's feature rows (hides global latency under GEMM2)
            if (more) {
                const float4_t* rp = (const float4_t*)(in_f + (size_t)nbN * 32 + 8 * g); f0 = rp[0]; f1 = rp[1];
                const float4_t* sp = (const float4_t*)(out_f + (size_t)sgN * 32 + 8 * g); g0 = sp[0]; g1 = sp[1];
            }
            const int tend = (et + 16 < eE) ? et + 16 : eE;
            const bool pure = (e0c <= et) && (e1c >= et + 16) && (et + 16 <= eE);
            if (pure) {
                // whole tile belongs to current segment: accumulate via MFMA C-in
                #pragma unroll
                for (int k2 = 0; k2 < 4; ++k2) {
                    bf16x8 ah = *(const bf16x8*)(lds + hrb + k2 * 64);
                    #pragma unroll
                    for (int u = 0; u < 4; ++u) colacc[u] = MFMA16(ah, w2f[u][k2], colacc[u]);
                }
                while (e1c <= tend) {   // close (e1c==tend) + any following empties
                    const int d = e1c - e0c;
                    const float inv = (d > 0) ? 1.0f / (float)d : 0.0f;
                    float* orow = out + (size_t)s * 64;
                    #pragma unroll
                    for (int u = 0; u < 4; ++u) {
                        float v = colacc[u][0] + colacc[u][1] + colacc[u][2] + colacc[u][3];
                        v += __shfl_xor(v, 16); v += __shfl_xor(v, 32);
                        if (g == 0) orow[u * 16 + c] = (d > 0) ? v * inv + b2r[u] : 0.0f;
                        colacc[u] = (f32x4){0.f, 0.f, 0.f, 0.f};
                    }
                    ++s; e0c = e1c;
                    if (s >= sB) break;
                    e1c = rsp[s + 1];
                }
            } else {
                // boundary tile: compute y then masked piece-accumulate + closes
                f32x4 y[4];
                #pragma unroll
                for (int u = 0; u < 4; ++u) y[u] = (f32x4){0.f, 0.f, 0.f, 0.f};
                #pragma unroll
                for (int k2 = 0; k2 < 4; ++k2) {
                    bf16x8 ah = *(const bf16x8*)(lds + hrb + k2 * 64);
                    #pragma unroll
                    for (int u = 0; u < 4; ++u) y[u] = MFMA16(ah, w2f[u][k2], y[u]);
                }
                while (true) {
                    int hi_p = ((e1c < tend) ? e1c : tend) - et;
                    int lo_p = e0c - et; if (lo_p < 0) lo_p = 0;
                    float m[4];
                    #pragma unroll
                    for (int j = 0; j < 4; ++j) {
                        int r = 4 * g + j;
                        m[j] = (r >= lo_p && r < hi_p) ? 1.0f : 0.0f;
                    }
                    #pragma unroll
                    for (int u = 0; u < 4; ++u)
                        #pragma unroll
                        for (int j = 0; j < 4; ++j)
                            colacc[u][j] = fmaf(y[u][j], m[j], colacc[u][j]);
                    if (e1c <= tend) {
                        const int d = e1c - e0c;
                        const float inv = (d > 0) ? 1.0f / (float)d : 0.0f;
                        float* orow = out + (size_t)s * 64;
                        #pragma unroll
                        for (int u = 0; u < 4; ++u) {
                            float v = colacc[u][0] + colacc[u][1] + colacc[u][2] + colacc[u][3];
                            v += __shfl_xor(v, 16); v += __shfl_xor(v, 32);
                            if (g == 0) orow[u * 16 + c] = (d > 0) ? v * inv + b2r[u] : 0.0f;
                            colacc[u] = (f32x4){0.f, 0.f, 0.f, 0.f};
                        }
                        ++s; e0c = e1c;
                        if (s >= sB) break;
                        e1c = rsp[s + 1];
                    } else break;
                }
            }
        }
    }
    // all-empty wave range (eS == eE): write zeros
    while (s < sB) {
        float* orow = out + (size_t)s * 64;
        if (g == 0) {
            #pragma unroll
            for (int u = 0; u < 4; ++u) orow[u * 16 + c] = 0.0f;
        }
        ++s;
    }
}

extern "C" void kernel_launch(void* const* d_in, const int* in_sizes, int n_in,
                              void* d_out, int out_size, void* d_ws, size_t ws_size,
                              hipStream_t stream) {
    const float* in_f  = (const float*)d_in[0];
    const float* out_f = (const float*)d_in[1];
    const float* W1    = (const float*)d_in[2];
    const float* b1    = (const float*)d_in[3];
    const float* W2    = (const float*)d_in[4];
    const float* b2    = (const float*)d_in[5];
    const int*   nbr   = (const int*)d_in[6];
    const int*   rsp   = (const int*)d_in[7];
    float* out = (float*)d_out;
    const int M = in_sizes[7] - 1;
    const int E = in_sizes[6];

    const int nblocks = 512;              // 2 blocks/CU at 2 waves/SIMD residency
    const int nwaves  = nblocks * 4;
    const int epw = (E + nwaves - 1) / nwaves;

    nmlp_kernel<<<dim3(nblocks), dim3(256), 0, stream>>>(in_f, out_f, W1, b1, W2, b2,
                                                         nbr, rsp, out, M, E, epw);
}